// Round 1
// baseline (240.975 us; speedup 1.0000x reference)
//
#include <hip/hip_runtime.h>

// Problem: latent (16,192,64,64) fp32, codebook (1024,192) fp32.
// N = 65536 points, D = 192, K = 1024.
// d_out = [quantized: 12582912 fp32][indices-as-float: 65536].

#define NPTS   65536
#define DIMS   192
#define KCB    1024
#define HW     4096
#define QELEMS 12582912

typedef __attribute__((ext_vector_type(8))) _Float16 f16x8;
typedef __attribute__((ext_vector_type(4))) _Float16 f16x4;
typedef __attribute__((ext_vector_type(4))) float f32x4;

// ============================ f16 MFMA path =============================
// Codebook rows are unit-normalized (c2[k] == 1), so argmin dist == argmax dot.
// q = cvt_u32(fma(dot, inv*2^20, 2^21)) -> q = 2^20*(cos'+2), cos' = inv*dot.
// Worst-case cos' err <= 2u*CS + accum ~ 1.05e-3 (u = 2^-11). Quant grid
// 2^-20 in cos'; MARGIN_Q = 2432 (Δcos' 2.32e-3) >= 2x bound -> narrow-gap
// points (est ~8k) get exact fp32 batched rescore (which uses true c2).
// (Same effective margin as the old dist-domain 4864: Δdist = 2Δcos'.)
#define MARGIN_Q 2432u

__device__ __forceinline__ void async_load16(const void* g, void* l) {
    __builtin_amdgcn_global_load_lds(
        (const __attribute__((address_space(1))) unsigned int*)g,
        (__attribute__((address_space(3))) unsigned int*)l, 16, 0, 0);
}

// running top-2 under MAX: b >= s; merge sorted pair (ob >= os).
__device__ __forceinline__ void top2_merge_max(unsigned& b, unsigned& s,
                                               unsigned ob, unsigned os) {
    unsigned nb = max(b, ob);
    unsigned ns = max(min(b, ob), max(s, os));
    b = nb; s = ns;
}

// ---- codebook -> f16, chunk-major [c][k][32] (chunk c = dims c*32..c*32+31) ----
__global__ __launch_bounds__(256) void k_prep_cb16(const float* __restrict__ cbk,
                                                   _Float16* __restrict__ Bpf) {
    int id = blockIdx.x * 256 + threadIdx.x;    // 196608
    if (id >= KCB * DIMS) return;
    int k = id / DIMS, d = id % DIMS;
    Bpf[((size_t)(d >> 5) * KCB + k) * 32 + (d & 31)] = (_Float16)cbk[id];
}

// ---- codebook row squared norms (rescore only) ----
__global__ __launch_bounds__(256) void k_c2(const float* __restrict__ cbk,
                                            float* __restrict__ c2) {
    int k = blockIdx.x * 256 + threadIdx.x;
    if (k >= KCB) return;
    const float4* row = (const float4*)(cbk + (size_t)k * DIMS);
    float s = 0.f;
    #pragma unroll
    for (int i = 0; i < DIMS / 4; ++i) {
        float4 v = row[i];
        s += v.x * v.x + v.y * v.y + v.z * v.z + v.w * v.w;
    }
    c2[k] = s;
}

// ---- transpose codebook fp32: cbkT[d][k] (for coalesced rescore) ----
__global__ __launch_bounds__(256) void k_cbT(const float* __restrict__ cbk,
                                             float* __restrict__ cbkT) {
    __shared__ float q[64 * 193];
    const int tid = threadIdx.x;
    const int k0 = blockIdx.x * 64;
    const int lane = tid & 63;
    const int grp = tid >> 6;
    for (int r = grp; r < 64; r += 4) {
        const float* row = cbk + (size_t)(k0 + r) * DIMS;
        for (int c = lane; c < DIMS; c += 64) q[r * 193 + c] = row[c];
    }
    __syncthreads();
    for (int d = grp; d < DIMS; d += 4) {
        cbkT[(size_t)d * KCB + k0 + lane] = q[lane * 193 + d];
    }
}

// ---- fused: latent->f16 LDS slab + reg-resident A + dbuf MFMA GEMM +
//      argmax + gather ----
// grid 512 (128 points each); 4 waves = 2x2 of 64x64 MFMA tiles.
// A fragments are hoisted to registers once (24 x f16x8 per lane); the
// K-loop reads only B from LDS (4 x ds_read_b128 per 16 MFMA) with a
// double-buffered 8 KB chunk pipeline and counted vmcnt (never drains to 0).
__global__ __launch_bounds__(256, 2) void k_gemm_f(const float* __restrict__ latent,
                                                   const _Float16* __restrict__ Bpf,
                                                   const float* __restrict__ cbk,
                                                   float* __restrict__ out_q,
                                                   float* __restrict__ idxf,
                                                   int* __restrict__ list,
                                                   int* __restrict__ cnt) {
    __shared__ __align__(16) _Float16 As[128 * 200];     // 51200 B (dead after hoist)
    __shared__ __align__(16) _Float16 Bs[2][128 * 32];   // 2 x 8192 B dbuf
    __shared__ float inv_s[128];
    __shared__ uint2 t2buf[256];
    __shared__ int sidx[128];

    const int tid = threadIdx.x;
    const int wave = tid >> 6;
    const int lane = tid & 63;
    const int quad = lane >> 4;
    const int l15 = lane & 15;
    const int wm = (wave >> 1) * 64;
    const int wn = (wave & 1) * 64;
    const int n0 = blockIdx.x * 128;
    const int bB = n0 >> 12;
    const int hw0 = n0 & 4095;

    // ---- phase 0: load raw latent slab once, f16-convert, ssq ----
    {
        float* part = (float*)&Bs[0][0];        // overlay (pre-K-loop)
        const float* lat = latent + (size_t)bB * DIMS * HW + hw0;
        const int p = tid & 127, ch = tid >> 7;
        float ss = 0.f;
        #pragma unroll 4
        for (int i = 0; i < 24; ++i) {
            int c0 = i * 8 + ch * 4;
            float v0 = lat[(size_t)(c0 + 0) * HW + p];
            float v1 = lat[(size_t)(c0 + 1) * HW + p];
            float v2 = lat[(size_t)(c0 + 2) * HW + p];
            float v3 = lat[(size_t)(c0 + 3) * HW + p];
            ss = fmaf(v0, v0, fmaf(v1, v1, fmaf(v2, v2, fmaf(v3, v3, ss))));
            f16x4 h = { (_Float16)v0, (_Float16)v1, (_Float16)v2, (_Float16)v3 };
            *(f16x4*)&As[p * 200 + c0] = h;
        }
        part[ch * 128 + p] = ss;
        __syncthreads();
        if (tid < 128)
            inv_s[tid] = 1.0f / (sqrtf(part[tid] + part[128 + tid]) + 1e-8f);
        __syncthreads();                        // part consumed before Bs reuse
    }

    // ---- hoist A fragments (this wave's 64 rows x 192 dims) to registers ----
    f16x8 af[6][4];
    #pragma unroll
    for (int c = 0; c < 6; ++c)
        #pragma unroll
        for (int mt = 0; mt < 4; ++mt)
            af[c][mt] = *(const f16x8*)&As[(wm + mt * 16 + l15) * 200 + c * 32 + quad * 8];

    // per-row quant scales: rows of acc are quad*4+r within each mt tile
    float scl[16];
    #pragma unroll
    for (int mt = 0; mt < 4; ++mt)
        #pragma unroll
        for (int r = 0; r < 4; ++r)
            scl[mt * 4 + r] = inv_s[wm + mt * 16 + quad * 4 + r] * 1048576.0f;

    unsigned rb[16], rs[16];
    #pragma unroll
    for (int i = 0; i < 16; ++i) { rb[i] = 0u; rs[i] = 0u; }

    int kn[4];
    #pragma unroll
    for (int nt = 0; nt < 4; ++nt) kn[nt] = wn + nt * 16 + l15;   // += 128 per nb

    // per-lane constant staging offsets (pre-swizzled global source, m173)
    const int u0 = tid, u1 = tid + 256;
    const int pu0 = (u0 & ~3) | ((u0 & 3) ^ ((u0 >> 2) & 3));
    const int pu1 = (u1 & ~3) | ((u1 & 3) ^ ((u1 >> 2) & 3));
    // swizzled bf read offset (f16 elements): row n=wn+nt*16+l15, unit quad^(n&3)
    const int bfo = (wn + l15) * 32 + ((quad ^ (l15 & 3)) * 8);

    // ---- prologue: stage chunks h=0 (nb0,c0) and h=1 (nb0,c1) ----
    {
        const _Float16* s0 = Bpf;                                  // (c=0,nb=0)
        async_load16(s0 + (size_t)pu0 * 8, &Bs[0][u0 * 8]);
        async_load16(s0 + (size_t)pu1 * 8, &Bs[0][u1 * 8]);
        const _Float16* s1 = Bpf + (size_t)KCB * 32;               // (c=1,nb=0)
        async_load16(s1 + (size_t)pu0 * 8, &Bs[1][u0 * 8]);
        async_load16(s1 + (size_t)pu1 * 8, &Bs[1][u1 * 8]);
    }
    int nb_s = 0, c_s = 2;                      // next chunk to stage (h=2)

    // ---- K-loop: nb (8 codeword strips) x c (6 dim chunks of 32) ----
    for (int nb = 0; nb < 8; ++nb) {
        f32x4 acc[4][4];
        #pragma unroll
        for (int mt = 0; mt < 4; ++mt)
            #pragma unroll
            for (int nt = 0; nt < 4; ++nt)
                #pragma unroll
                for (int r = 0; r < 4; ++r) acc[mt][nt][r] = 0.f;

        #pragma unroll
        for (int c = 0; c < 6; ++c) {
            // wait for buf[h&1]'s 2 loads; keep next chunk's 2 in flight
            if (c == 5 && nb == 7) {
                asm volatile("s_waitcnt vmcnt(0)" ::: "memory");
            } else {
                asm volatile("s_waitcnt vmcnt(2)" ::: "memory");
            }
            __builtin_amdgcn_s_barrier();       // tile visible to all waves
            const int buf = (nb * 6 + c) & 1;
            f16x8 bf[4];
            #pragma unroll
            for (int nt = 0; nt < 4; ++nt)
                bf[nt] = *(const f16x8*)&Bs[buf][bfo + nt * 512];
            #pragma unroll
            for (int mt = 0; mt < 4; ++mt)
                #pragma unroll
                for (int nt = 0; nt < 4; ++nt)
                    acc[mt][nt] = __builtin_amdgcn_mfma_f32_16x16x32_f16(
                        af[c][mt], bf[nt], acc[mt][nt], 0, 0, 0);
            asm volatile("s_waitcnt lgkmcnt(0)" ::: "memory");  // bf reads done
            __builtin_amdgcn_s_barrier();       // all waves done reading buf
            if (!((c >= 4) && nb == 7)) {       // stage h+2 into freed buffer
                const _Float16* src = Bpf + ((size_t)c_s * KCB + nb_s * 128) * 32;
                async_load16(src + (size_t)pu0 * 8, &Bs[buf][u0 * 8]);
                async_load16(src + (size_t)pu1 * 8, &Bs[buf][u1 * 8]);
                if (++c_s == 6) { c_s = 0; ++nb_s; }
            }
        }

        // per-nb epilogue: q = cvt_u32(dot*inv*2^20 + 2^21); max top-2 merge
        #pragma unroll
        for (int mt = 0; mt < 4; ++mt) {
            #pragma unroll
            for (int r = 0; r < 4; ++r) {
                float sc = scl[mt * 4 + r];
                unsigned p0 = ((unsigned)fmaf(acc[mt][0][r], sc, 2097152.0f) << 10) | (unsigned)kn[0];
                unsigned p1 = ((unsigned)fmaf(acc[mt][1][r], sc, 2097152.0f) << 10) | (unsigned)kn[1];
                unsigned p2 = ((unsigned)fmaf(acc[mt][2][r], sc, 2097152.0f) << 10) | (unsigned)kn[2];
                unsigned p3 = ((unsigned)fmaf(acc[mt][3][r], sc, 2097152.0f) << 10) | (unsigned)kn[3];
                unsigned b01 = max(p0, p1), s01 = min(p0, p1);
                unsigned b23 = max(p2, p3), s23 = min(p2, p3);
                unsigned bb = max(b01, b23);
                unsigned s4 = max(min(b01, b23), max(s01, s23));
                top2_merge_max(rb[mt * 4 + r], rs[mt * 4 + r], bb, s4);
            }
        }
        #pragma unroll
        for (int nt = 0; nt < 4; ++nt) kn[nt] += 128;
    }

    // ---- cross-lane / cross-wave top-2 merge ----
    __syncthreads();
    #pragma unroll
    for (int i = 0; i < 16; ++i) {
        unsigned b = rb[i], s = rs[i];
        #pragma unroll
        for (int off = 1; off < 16; off <<= 1) {
            unsigned ob = __shfl_xor(b, off, 64);
            unsigned os = __shfl_xor(s, off, 64);
            top2_merge_max(b, s, ob, os);
        }
        if (l15 == 0) {
            int mt = i >> 2, r = i & 3;
            int mloc = wm + mt * 16 + quad * 4 + r;
            t2buf[mloc * 2 + (wave & 1)] = make_uint2(b, s);
        }
    }
    __syncthreads();
    if (tid < 128) {
        uint2 x = t2buf[tid * 2];
        uint2 y = t2buf[tid * 2 + 1];
        unsigned b = x.x, s = x.y;
        top2_merge_max(b, s, y.x, y.y);
        int k = (int)(b & 1023u);
        sidx[tid] = k;
        idxf[n0 + tid] = (float)k;
        if (((b >> 10) - (s >> 10)) < MARGIN_Q) {
            int pos = atomicAdd(cnt, 1);
            list[pos] = n0 + tid;
        }
    }
    __syncthreads();

    // ---- gather epilogue (q overlays As) ----
    float* q = (float*)As;                      // 32*193*4 = 24.7 KB
    for (int chk = 0; chk < 4; ++chk) {
        int p0 = chk * 32;
        for (int r = wave; r < 32; r += 4) {
            const float* row = cbk + (size_t)sidx[p0 + r] * DIMS;
            for (int c = lane; c < DIMS; c += 64) q[r * 193 + c] = row[c];
        }
        __syncthreads();
        float* ob = out_q + (size_t)bB * DIMS * HW + hw0 + p0;
        #pragma unroll
        for (int i = 0; i < 24; ++i) {
            int u = i * 256 + tid;
            int c = u >> 5, p = u & 31;
            ob[(size_t)c * HW + p] = q[p * 193 + c];
        }
        __syncthreads();
    }
}

// ---- batched exact fp32 rescore: 16 flagged points per block ----
__global__ __launch_bounds__(256) void k_rescore16(const float* __restrict__ latent,
                                                   const float* __restrict__ cbkT,
                                                   const float* __restrict__ cbk,
                                                   const float* __restrict__ c2,
                                                   const int* __restrict__ list,
                                                   const int* __restrict__ cnt,
                                                   float* __restrict__ out_q,
                                                   float* __restrict__ idxf) {
    __shared__ float xs[16][200];
    __shared__ float part[16][16];
    __shared__ float inv_s[16];
    __shared__ unsigned long long best[16];
    const int tid = threadIdx.x;
    const int count = *cnt;
    const float4* ct = (const float4*)cbkT;     // [d][256] float4
    const int j = tid >> 4, dl = tid & 15;

    for (int base = blockIdx.x * 16; base < count; base += gridDim.x * 16) {
        __syncthreads();                        // guard xs/best reuse
        float ss = 0.f;
        int n = 0, bb = 0, hw = 0;
        bool valid = (base + j) < count;
        if (valid) {
            n = list[base + j]; bb = n >> 12; hw = n & 4095;
            #pragma unroll
            for (int i = 0; i < 12; ++i) {
                int d = dl + i * 16;
                float v = latent[((size_t)bb * DIMS + d) * HW + hw];
                xs[j][d] = v;
                ss = fmaf(v, v, ss);
            }
        }
        part[j][dl] = ss;
        if (tid < 16) best[tid] = ~0ull;
        __syncthreads();
        if (tid < 16) {
            float s = 0.f;
            #pragma unroll
            for (int i = 0; i < 16; ++i) s += part[tid][i];
            inv_s[tid] = 1.0f / (sqrtf(s) + 1e-8f);
        }
        __syncthreads();

        // dots: thread owns codewords 4*tid..4*tid+3 for all 16 points
        float4 a[16];
        #pragma unroll
        for (int p = 0; p < 16; ++p) a[p] = make_float4(0.f, 0.f, 0.f, 0.f);
        for (int d = 0; d < DIMS; d += 4) {
            float4 cv0 = ct[(size_t)(d + 0) * 256 + tid];
            float4 cv1 = ct[(size_t)(d + 1) * 256 + tid];
            float4 cv2 = ct[(size_t)(d + 2) * 256 + tid];
            float4 cv3 = ct[(size_t)(d + 3) * 256 + tid];
            #pragma unroll
            for (int p = 0; p < 16; ++p) {
                float4 xv = *(const float4*)&xs[p][d];
                a[p].x = fmaf(xv.x, cv0.x, a[p].x); a[p].y = fmaf(xv.x, cv0.y, a[p].y);
                a[p].z = fmaf(xv.x, cv0.z, a[p].z); a[p].w = fmaf(xv.x, cv0.w, a[p].w);
                a[p].x = fmaf(xv.y, cv1.x, a[p].x); a[p].y = fmaf(xv.y, cv1.y, a[p].y);
                a[p].z = fmaf(xv.y, cv1.z, a[p].z); a[p].w = fmaf(xv.y, cv1.w, a[p].w);
                a[p].x = fmaf(xv.z, cv2.x, a[p].x); a[p].y = fmaf(xv.z, cv2.y, a[p].y);
                a[p].z = fmaf(xv.z, cv2.z, a[p].z); a[p].w = fmaf(xv.z, cv2.w, a[p].w);
                a[p].x = fmaf(xv.w, cv3.x, a[p].x); a[p].y = fmaf(xv.w, cv3.y, a[p].y);
                a[p].z = fmaf(xv.w, cv3.z, a[p].z); a[p].w = fmaf(xv.w, cv3.w, a[p].w);
            }
        }
        #pragma unroll
        for (int p = 0; p < 16; ++p) {
            float inv = inv_s[p];
            float dot4[4] = {a[p].x, a[p].y, a[p].z, a[p].w};
            unsigned long long loc = ~0ull;
            #pragma unroll
            for (int e = 0; e < 4; ++e) {
                int k = 4 * tid + e;
                float dist = c2[k] - 2.f * inv * dot4[e];
                unsigned ub = __float_as_uint(dist);
                ub ^= (ub >> 31) ? 0xFFFFFFFFu : 0x80000000u;   // monotonic
                unsigned long long pk =
                    ((unsigned long long)ub << 32) | (unsigned)k;
                loc = loc < pk ? loc : pk;
            }
            #pragma unroll
            for (int off = 1; off < 64; off <<= 1) {
                unsigned long long o = __shfl_xor(loc, off, 64);
                loc = loc < o ? loc : o;
            }
            if ((tid & 63) == 0) atomicMin(&best[p], loc);
        }
        __syncthreads();
        if (valid) {
            int kk = (int)(best[j] & 0xFFFFFFFFull);
            #pragma unroll
            for (int i = 0; i < 12; ++i) {
                int d = dl + i * 16;
                out_q[((size_t)bb * DIMS + d) * HW + hw] = cbk[(size_t)kk * DIMS + d];
            }
            if (dl == 0) idxf[n] = (float)kk;
        }
    }
}

// ======================= fallback fp32 path (round-1) ====================
__global__ __launch_bounds__(256) void k_norms_fb(const float* __restrict__ latent,
                                                  float* __restrict__ inv_norm) {
    __shared__ float red[256];
    const int tid = threadIdx.x;
    const int n0 = blockIdx.x * 128;
    const int nl = tid & 127;
    const int half = tid >> 7;
    const int b = n0 >> 12;
    const int hw = (n0 & 4095) + nl;
    const float* base = latent + (size_t)b * DIMS * HW + hw;
    float ssq = 0.f;
    for (int c = half; c < DIMS; c += 2) {
        float v = base[(size_t)c * HW];
        ssq = fmaf(v, v, ssq);
    }
    red[tid] = ssq;
    __syncthreads();
    if (half == 0) {
        float s = red[tid] + red[tid + 128];
        inv_norm[n0 + nl] = 1.0f / (sqrtf(s) + 1e-8f);
    }
}

#define LDX  132
__global__ __launch_bounds__(256) void k_dist_fb(const float* __restrict__ latent,
                                                 const float* __restrict__ cbk,
                                                 const float* __restrict__ inv_norm,
                                                 const float* __restrict__ c2,
                                                 int* __restrict__ idx_out,
                                                 float* __restrict__ idxf_out) {
    __shared__ __align__(16) float xsm[64 * LDX];
    __shared__ __align__(16) float csm[64 * LDX];
    __shared__ unsigned long long red[128];
    const int tid = threadIdx.x;
    const int n0 = blockIdx.x * 128;
    const int b = n0 >> 12;
    const int hw0 = n0 & 4095;
    const int kt = tid & 15;
    const int mt = tid >> 4;
    const float* lat_base = latent + (size_t)b * DIMS * HW + hw0;
    float inv[8];
    #pragma unroll
    for (int i = 0; i < 8; ++i) inv[i] = inv_norm[n0 + mt * 8 + i];
    float best[8];
    int bidx[8];
    #pragma unroll
    for (int i = 0; i < 8; ++i) { best[i] = 3.4e38f; bidx[i] = 0; }
    const int nl = tid & 127;
    const int cp = tid >> 7;
    for (int k0 = 0; k0 < KCB; k0 += 128) {
        float acc[8][8];
        #pragma unroll
        for (int i = 0; i < 8; ++i)
            #pragma unroll
            for (int j = 0; j < 8; ++j) acc[i][j] = 0.f;
        for (int d0 = 0; d0 < DIMS; d0 += 64) {
            __syncthreads();
            for (int cc = cp; cc < 64; cc += 2)
                xsm[cc * LDX + nl] = lat_base[(size_t)(d0 + cc) * HW + nl];
            #pragma unroll
            for (int i = 0; i < 8; ++i) {
                int f4 = tid + 256 * i;
                int kk = f4 >> 4;
                int dq = f4 & 15;
                float4 v = *(const float4*)(cbk + (size_t)(k0 + kk) * DIMS + d0 + dq * 4);
                csm[(dq * 4 + 0) * LDX + kk] = v.x;
                csm[(dq * 4 + 1) * LDX + kk] = v.y;
                csm[(dq * 4 + 2) * LDX + kk] = v.z;
                csm[(dq * 4 + 3) * LDX + kk] = v.w;
            }
            __syncthreads();
            for (int d = 0; d < 64; ++d) {
                const float* xr = &xsm[d * LDX + mt * 8];
                const float* cr = &csm[d * LDX + kt * 8];
                float x8[8], c8[8];
                *(float4*)&x8[0] = *(const float4*)&xr[0];
                *(float4*)&x8[4] = *(const float4*)&xr[4];
                *(float4*)&c8[0] = *(const float4*)&cr[0];
                *(float4*)&c8[4] = *(const float4*)&cr[4];
                #pragma unroll
                for (int i = 0; i < 8; ++i)
                    #pragma unroll
                    for (int j = 0; j < 8; ++j)
                        acc[i][j] = fmaf(x8[i], c8[j], acc[i][j]);
            }
        }
        float cc2[8];
        #pragma unroll
        for (int j = 0; j < 8; ++j) cc2[j] = c2[k0 + kt * 8 + j];
        #pragma unroll
        for (int i = 0; i < 8; ++i)
            #pragma unroll
            for (int j = 0; j < 8; ++j) {
                float t = inv[i] * acc[i][j];
                float dist = fmaf(-2.f, t, cc2[j]);
                int kidx = k0 + kt * 8 + j;
                if (dist < best[i]) { best[i] = dist; bidx[i] = kidx; }
            }
    }
    if (tid < 128) red[tid] = ~0ull;
    __syncthreads();
    #pragma unroll
    for (int i = 0; i < 8; ++i) {
        unsigned long long p =
            ((unsigned long long)__float_as_uint(best[i]) << 32) | (unsigned)bidx[i];
        atomicMin(&red[mt * 8 + i], p);
    }
    __syncthreads();
    if (tid < 128) {
        int k = (int)(red[tid] & 0xFFFFFFFFu);
        idx_out[n0 + tid] = k;
        idxf_out[n0 + tid] = (float)k;
    }
}

__global__ __launch_bounds__(256) void k_gather(const float* __restrict__ cbk,
                                                const int* __restrict__ idx,
                                                float* __restrict__ out) {
    __shared__ float q[64 * 193];
    __shared__ int sidx[64];
    const int tid = threadIdx.x;
    const int n0 = blockIdx.x * 64;
    const int b = n0 >> 12;
    const int hw0 = n0 & 4095;
    const int lane = tid & 63;
    const int grp = tid >> 6;

    if (tid < 64) sidx[tid] = idx[n0 + tid];
    __syncthreads();
    for (int r = grp; r < 64; r += 4) {
        const float* row = cbk + (size_t)sidx[r] * DIMS;
        for (int c = lane; c < DIMS; c += 64) q[r * 193 + c] = row[c];
    }
    __syncthreads();
    float* obase = out + (size_t)b * DIMS * HW + hw0;
    for (int c = grp; c < DIMS; c += 4) {
        obase[(size_t)c * HW + lane] = q[lane * 193 + c];
    }
}

// ================================ launch ================================
extern "C" void kernel_launch(void* const* d_in, const int* in_sizes, int n_in,
                              void* d_out, int out_size, void* d_ws, size_t ws_size,
                              hipStream_t stream) {
    const float* latent = (const float*)d_in[0];
    const float* cbk = (const float*)d_in[1];
    float* out = (float*)d_out;
    float* out_q = out;
    float* out_idx = out + QELEMS;

    if (ws_size >= 2u * 1024u * 1024u) {
        // ws layout (bytes):
        char* w = (char*)d_ws;
        _Float16* Bpf = (_Float16*)w;                          //    393,216
        float* cbkT = (float*)(w + 393216);                    //    786,432
        float* c2 = (float*)(w + 1179648);                     //      4,096
        int* list = (int*)(w + 1183744);                       //    262,144
        int* cnt = (int*)(w + 1445888);                        //          4

        hipMemsetAsync(cnt, 0, 4, stream);
        k_prep_cb16<<<768, 256, 0, stream>>>(cbk, Bpf);
        k_c2<<<4, 256, 0, stream>>>(cbk, c2);
        k_cbT<<<KCB / 64, 256, 0, stream>>>(cbk, cbkT);
        k_gemm_f<<<512, 256, 0, stream>>>(latent, Bpf, cbk, out_q, out_idx,
                                          list, cnt);
        k_rescore16<<<512, 256, 0, stream>>>(latent, cbkT, cbk, c2, list, cnt,
                                             out_q, out_idx);
    } else {
        float* inv_norm = (float*)d_ws;
        float* c2 = inv_norm + NPTS;
        int* idx = (int*)(c2 + KCB);
        k_norms_fb<<<NPTS / 128, 256, 0, stream>>>(latent, inv_norm);
        k_c2<<<4, 256, 0, stream>>>(cbk, c2);
        k_dist_fb<<<NPTS / 128, 256, 0, stream>>>(latent, cbk, inv_norm, c2, idx, out_idx);
        k_gather<<<NPTS / 64, 256, 0, stream>>>(cbk, idx, out_q);
    }
}